// Round 12
// baseline (18.892 us; speedup 1.0000x reference)
//
#include <hip/hip_runtime.h>

#define R 128
#define C 256
#define P 7
#define HW 64
#define SROW 68                     // slab row stride (floats): 16B-aligned, pads reads
#define SLAB (4 * P * SROW + 8)     // 4 channels x 7 bands + tail pad

__global__ __launch_bounds__(256) void
roi_pool_kernel(const float* __restrict__ x,
                const int* __restrict__ rois,
                float* __restrict__ out) {
    const int lane = threadIdx.x & 63;
    const int wid  = __builtin_amdgcn_readfirstlane(threadIdx.x >> 6);
    const int gw   = blockIdx.x * 4 + wid;    // wave id = r*64 + cq
    const int cq = gw & 63;                   // channel quad: channels 4cq..4cq+3
    const int r  = gw >> 6;
    const int c0 = cq << 2;

    __shared__ float vmbuf[4][SLAB];          // 29.9 KB/block
    float* slab = vmbuf[wid];

    const int rx = rois[r * 4 + 0];           // r uniform -> s_loads
    const int ry = rois[r * 4 + 1];
    const int rw = rois[r * 4 + 2];
    const int rh = rois[r * 4 + 3];

    // Match JAX: f32 rn divide; floor(coord + i*rl) with separate rn mul+add.
    const float rlx = (float)rw / 7.0f;
    const float rly = (float)rh / 7.0f;
    const int kw = __builtin_amdgcn_readfirstlane((int)rlx);  // floor(rl), 1..8
    const int kh = __builtin_amdgcn_readfirstlane((int)rly);

    // Band starts: lane plays py for lanes 0..6; readlanes hoisted (uniform).
    const int syv = (int)floorf(__fadd_rn((float)ry, __fmul_rn((float)lane, rly)));
    const int sy0 = __builtin_amdgcn_readlane(syv, 0);
    const int sy1 = __builtin_amdgcn_readlane(syv, 1);
    const int sy2 = __builtin_amdgcn_readlane(syv, 2);
    const int sy3 = __builtin_amdgcn_readlane(syv, 3);
    const int sy4 = __builtin_amdgcn_readlane(syv, 4);
    const int sy5 = __builtin_amdgcn_readlane(syv, 5);
    const int sy6 = __builtin_amdgcn_readlane(syv, 6);

    const int ch = lane >> 4;                 // 0..3 (channel within quad)
    const int g  = lane & 15;                 // 0..15 (column quad)
    const float* xch = x + ((size_t)(c0 + ch) << 12) + (g << 2);
    const float NEG = -3.402823466e38f;
    const float4 NEG4 = make_float4(NEG, NEG, NEG, NEG);

#define MAX4(a, b) make_float4(fmaxf((a).x,(b).x), fmaxf((a).y,(b).y), \
                               fmaxf((a).z,(b).z), fmaxf((a).w,(b).w))

    // ---- Phase 1: vertical band maxes, float4 per lane, 4 channels/wave ----
    // Loads always in-bounds (full 64-wide rows, sy(6)+7 <= 62). KH rows
    // loaded unconditionally (batched), rows >= kh discarded via cndmask.
#define BAND(PY, SY, KH)                                                      \
    {                                                                         \
        const float4* p = (const float4*)(xch + (SY) * HW);                   \
        float4 v[KH];                                                         \
        _Pragma("unroll")                                                     \
        for (int j = 0; j < KH; ++j) v[j] = p[j * 16];                        \
        float4 m = v[0];                     /* kh >= 1: row 0 always kept */ \
        _Pragma("unroll")                                                     \
        for (int j = 1; j < KH; ++j) {                                        \
            float4 t = (j < kh) ? v[j] : NEG4;                                \
            m = MAX4(m, t);                                                   \
        }                                                                     \
        *(float4*)(&slab[(ch * P + (PY)) * SROW + (g << 2)]) = m;             \
    }

    if (kh <= 4) {
        BAND(0,sy0,4) BAND(1,sy1,4) BAND(2,sy2,4) BAND(3,sy3,4)
        BAND(4,sy4,4) BAND(5,sy5,4) BAND(6,sy6,4)
    } else {
        BAND(0,sy0,8) BAND(1,sy1,8) BAND(2,sy2,8) BAND(3,sy3,8)
        BAND(4,sy4,8) BAND(5,sy5,8) BAND(6,sy6,8)
    }
#undef BAND

    // ---- Phase 2: 49 lanes x 4 channels; shared vaddr + imm-offset reads ----
    // Kept slots [sx, sx+kw) always lie in written cols [0,64); overshoot
    // reads stay inside the 68-float row (+ tail pad) and are discarded.
    if (lane < P * P) {
        const int py = lane / 7;
        const int px = lane - py * 7;
        const int sx = (int)floorf(__fadd_rn((float)rx, __fmul_rn((float)px, rlx)));
        const float* wp = slab + py * SROW + sx;       // per-ch: + ch*P*SROW
        const size_t obase = ((size_t)(r << 8) + c0) * (P * P) + lane;

        #pragma unroll
        for (int cc = 0; cc < 4; ++cc) {
            const float* w = wp + cc * (P * SROW);
            float m;
            if (kw <= 4) {
                float a0 = w[0], a1 = w[1], a2 = w[2], a3 = w[3];
                m = a0;
                m = fmaxf(m, (1 < kw) ? a1 : NEG);
                m = fmaxf(m, (2 < kw) ? a2 : NEG);
                m = fmaxf(m, (3 < kw) ? a3 : NEG);
            } else {
                float a0 = w[0], a1 = w[1], a2 = w[2], a3 = w[3];
                float a4 = w[4], a5 = w[5], a6 = w[6], a7 = w[7];
                m = fmaxf(fmaxf(fmaxf(a0, a1), fmaxf(a2, a3)), a4);  // kw >= 5
                m = fmaxf(m, (5 < kw) ? a5 : NEG);
                m = fmaxf(m, (6 < kw) ? a6 : NEG);
                m = fmaxf(m, (7 < kw) ? a7 : NEG);
            }
            out[obase + cc * (P * P)] = m;   // 196B contiguous per store
        }
    }
}

extern "C" void kernel_launch(void* const* d_in, const int* in_sizes, int n_in,
                              void* d_out, int out_size, void* d_ws, size_t ws_size,
                              hipStream_t stream) {
    const float* x = (const float*)d_in[0];
    const int* rois = (const int*)d_in[1];
    float* out = (float*)d_out;

    const int grid = (R * C / 4) / 4;  // 8192 waves (r x 64 ch-quads), 4/block
    roi_pool_kernel<<<grid, 256, 0, stream>>>(x, rois, out);
}

// Round 13
// 17.463 us; speedup vs baseline: 1.0819x; 1.0819x over previous
//
#include <hip/hip_runtime.h>

#define R 128
#define C 256
#define P 7
#define HW 64
#define SW 72   // slab row stride: phase-2 reads reach sx+7 <= 62 < 72

__global__ __launch_bounds__(256) void
roi_pool_kernel(const float* __restrict__ x,
                const int* __restrict__ rois,
                float* __restrict__ out) {
    const int lane = threadIdx.x & 63;
    const int wid  = __builtin_amdgcn_readfirstlane(threadIdx.x >> 6);
    const int half = wid & 1;                 // 0: bands 0-3 (+phase 2), 1: bands 4-6
    const int tb   = blockIdx.x * 2 + (wid >> 1);   // task id = r*C + c
    const int c = tb & (C - 1);
    const int r = tb >> 8;

    __shared__ float vmbuf[2][P * SW];        // 4.03 KB/block
    float* slab = vmbuf[wid >> 1];

    const int rx = rois[r * 4 + 0];           // r uniform per wave -> s_loads
    const int ry = rois[r * 4 + 1];
    const int rw = rois[r * 4 + 2];
    const int rh = rois[r * 4 + 3];

    // Match JAX: f32 rn divide; floor(coord + i*rl) with separate rn mul+add.
    const float rlx = (float)rw / 7.0f;
    const float rly = (float)rh / 7.0f;
    const int kw = __builtin_amdgcn_readfirstlane((int)rlx);  // floor(rl), 1..8
    const int kh = __builtin_amdgcn_readfirstlane((int)rly);

    // Band starts: lane plays py for lanes 0..6, then readlane -> SGPR.
    const int syv = (int)floorf(__fadd_rn((float)ry, __fmul_rn((float)lane, rly)));

    const float* xc = x + (size_t)c * (HW * HW);
    const float NEG = -3.402823466e38f;

    // ---- Phase 1: this wave's bands; lane = column (coalesced loads). ----
    // KH rows loaded unconditionally (always in-bounds: sy(6)+7 <= 62),
    // rows >= kh discarded branch-free.
#define BAND(PY, KH)                                                         \
    {                                                                        \
        const int sy = __builtin_amdgcn_readlane(syv, PY);                   \
        const float* p = xc + sy * HW + lane;                                \
        float v[KH];                                                         \
        _Pragma("unroll")                                                    \
        for (int j = 0; j < KH; ++j) v[j] = p[j * HW];                       \
        float vm = v[0];                      /* kh >= 1 */                  \
        _Pragma("unroll")                                                    \
        for (int j = 1; j < KH; ++j) vm = fmaxf(vm, (j < kh) ? v[j] : NEG);  \
        slab[(PY) * SW + lane] = vm;                                         \
    }

    if (half == 0) {                          // wave-uniform branch
        if (kh <= 4) { BAND(0,4) BAND(1,4) BAND(2,4) BAND(3,4) }
        else         { BAND(0,8) BAND(1,8) BAND(2,8) BAND(3,8) }
    } else {
        if (kh <= 4) { BAND(4,4) BAND(5,4) BAND(6,4) }
        else         { BAND(4,8) BAND(5,8) BAND(6,8) }
    }
#undef BAND

    __syncthreads();                          // slab complete (both halves)

    // ---- Phase 2: half-0 wave of each task; one lane per output bin. ----
    // All 8 reads land in written cols [0,64) (sx+7 <= 62); slots >= kw
    // discarded branch-free.
    if (half == 0 && lane < P * P) {
        const int py = lane / 7;
        const int px = lane - py * 7;
        const int sx = (int)floorf(__fadd_rn((float)rx, __fmul_rn((float)px, rlx)));
        const float* w = slab + py * SW + sx;
        float m;
        if (kw <= 4) {
            float a0 = w[0], a1 = w[1], a2 = w[2], a3 = w[3];
            m = a0;
            m = fmaxf(m, (1 < kw) ? a1 : NEG);
            m = fmaxf(m, (2 < kw) ? a2 : NEG);
            m = fmaxf(m, (3 < kw) ? a3 : NEG);
        } else {
            float a0 = w[0], a1 = w[1], a2 = w[2], a3 = w[3];
            float a4 = w[4], a5 = w[5], a6 = w[6], a7 = w[7];
            m = fmaxf(fmaxf(fmaxf(a0, a1), fmaxf(a2, a3)), a4);   // kw >= 5
            m = fmaxf(m, (5 < kw) ? a5 : NEG);
            m = fmaxf(m, (6 < kw) ? a6 : NEG);
            m = fmaxf(m, (7 < kw) ? a7 : NEG);
        }
        out[(size_t)tb * (P * P) + lane] = m; // 196B contiguous per task
    }
}

extern "C" void kernel_launch(void* const* d_in, const int* in_sizes, int n_in,
                              void* d_out, int out_size, void* d_ws, size_t ws_size,
                              hipStream_t stream) {
    const float* x = (const float*)d_in[0];
    const int* rois = (const int*)d_in[1];
    float* out = (float*)d_out;

    const int grid = R * C / 2;   // 16384 blocks; 2 tasks x 2 waves each
    roi_pool_kernel<<<grid, 256, 0, stream>>>(x, rois, out);
}